// Round 2
// baseline (202.977 us; speedup 1.0000x reference)
//
#include <hip/hip_runtime.h>
#include <hip/hip_bf16.h>
#include <stdint.h>

typedef __hip_bfloat16 bf16;
typedef float f32x4 __attribute__((ext_vector_type(4)));
typedef short bf16x8 __attribute__((ext_vector_type(8)));

#define NB 16384
#define NA 16
#define ND 512
#define NH 512

// workspace layout (bytes)
#define W1S_OFF 0u
#define W2S_OFF 8388608u
#define PERM_OFF 16777216u
#define META_OFF 16842752u
// meta ints: [0..15]=cnt, [16..32]=off (off[0]=0), [33..49]=blkoff (blkoff[0]=0), [50..65]=cursor

__device__ __forceinline__ unsigned short f2b(float x) {
  unsigned int b = __float_as_uint(x);
  return (unsigned short)((b + 0x7FFFu + ((b >> 16) & 1u)) >> 16);  // RNE
}

// ---------------- prep: W[a][d][h] f32 -> Wt[a][h][d] bf16 (transpose + cast) -------------
__global__ __launch_bounds__(256) void k_prep(const float* __restrict__ W1,
                                              const float* __restrict__ W2,
                                              bf16* __restrict__ W1s,
                                              bf16* __restrict__ W2s) {
  __shared__ float tile[64][65];
  int blk = blockIdx.x;          // 0..2047
  int m = blk >> 6;              // matrix 0..31 (16 W1 + 16 W2)
  int tl = blk & 63;
  int td = tl >> 3, th = tl & 7; // 64x64 tile coords
  const float* src = (m < NA) ? (W1 + (size_t)m * (ND * NH)) : (W2 + (size_t)(m - NA) * (ND * NH));
  bf16* dst = (m < NA) ? (W1s + (size_t)m * (ND * NH)) : (W2s + (size_t)(m - NA) * (ND * NH));
  int t = threadIdx.x;
  int r = t >> 2, c0 = (t & 3) << 4;
  const float* sp = src + (size_t)(td * 64 + r) * NH + th * 64 + c0;
  float4 v0 = ((const float4*)sp)[0];
  float4 v1 = ((const float4*)sp)[1];
  float4 v2 = ((const float4*)sp)[2];
  float4 v3 = ((const float4*)sp)[3];
  float* tr = &tile[r][c0];
  tr[0] = v0.x; tr[1] = v0.y; tr[2] = v0.z; tr[3] = v0.w;
  tr[4] = v1.x; tr[5] = v1.y; tr[6] = v1.z; tr[7] = v1.w;
  tr[8] = v2.x; tr[9] = v2.y; tr[10] = v2.z; tr[11] = v2.w;
  tr[12] = v3.x; tr[13] = v3.y; tr[14] = v3.z; tr[15] = v3.w;
  __syncthreads();
  int hloc = t >> 2, dc = (t & 3) << 4;
  union { unsigned short us[16]; uint4 q[2]; } u;
#pragma unroll
  for (int i = 0; i < 16; ++i) u.us[i] = f2b(tile[dc + i][hloc]);
  uint4* dp = (uint4*)(dst + (size_t)(th * 64 + hloc) * ND + td * 64 + dc);
  dp[0] = u.q[0];
  dp[1] = u.q[1];
}

// ---------------- sort-by-action helpers ----------------
__global__ void k_hist(const int* __restrict__ act, int* __restrict__ meta) {
  int i = blockIdx.x * blockDim.x + threadIdx.x;
  atomicAdd(&meta[act[i] & 15], 1);
}

__global__ void k_scan(int* __restrict__ meta) {
  int off = 0, bo = 0;
  meta[16] = 0;
  meta[33] = 0;
  for (int a = 0; a < 16; ++a) {
    int c = meta[a];
    off += c;
    meta[17 + a] = off;
    bo += (c + 63) >> 6;
    meta[34 + a] = bo;
  }
}

__global__ void k_scatter(const int* __restrict__ act, int* __restrict__ meta,
                          int* __restrict__ perm) {
  int i = blockIdx.x * blockDim.x + threadIdx.x;
  int a = act[i] & 15;
  int pos = atomicAdd(&meta[50 + a], 1);
  perm[meta[16 + a] + pos] = i;
}

// ---------------- fused grouped MLP ----------------
// block: one 64-row tile of one action. 512 threads = 8 waves.
// LDS: Xs [64][512] bf16 (swizzled) @0, H1s same @65536. outbuf aliases Xs (dead in layer2).
// wave w: output rows h in [w*64, w*64+64), all 64 batch cols. A (weights) streamed from
// global L2; B (activations) from LDS. mfma_f32_16x16x32_bf16, C layout: n=lane&15, m=(lane>>4)*4+i.
__global__ __launch_bounds__(512, 2) void k_main(
    const float* __restrict__ state, const float* __restrict__ b1,
    const float* __restrict__ b2, const float* __restrict__ W3,
    const float* __restrict__ b3, const bf16* __restrict__ W1s,
    const bf16* __restrict__ W2s, const int* __restrict__ perm,
    const int* __restrict__ meta, float* __restrict__ out) {
  extern __shared__ char smem[];
  char* Xs = smem;
  char* H1s = smem + 65536;
  float* outbuf = (float*)smem;  // [8][64] f32, written in layer-2 epilogue (Xs dead)

  int g = blockIdx.x;
  if (g >= meta[49]) return;  // beyond total tiles
  int a = 0;
  while (meta[34 + a] <= g) ++a;  // blkoff[a] <= g < blkoff[a+1]
  int t0 = g - meta[33 + a];
  int rowbase = meta[16 + a] + (t0 << 6);
  int nrows = meta[a] - (t0 << 6);
  nrows = nrows > 64 ? 64 : nrows;

  int tid = threadIdx.x;
  int lane = tid & 63;
  int w = tid >> 6;
  int l15 = lane & 15, l4 = lane >> 4;

  // ---- stage X tile -> LDS bf16, swizzle byte ^= (row&7)<<4 ----
  {
    int r = tid >> 3;
    int gr = (r < nrows) ? perm[rowbase + r] : -1;
    const float* srow = state + (size_t)(gr < 0 ? 0 : gr) * ND;
#pragma unroll
    for (int it = 0; it < 16; ++it) {
      int c8 = (tid & 7) + (it << 3);  // float4 chunk 0..127
      float4 v = make_float4(0.f, 0.f, 0.f, 0.f);
      if (gr >= 0) v = *(const float4*)(srow + (c8 << 2));
      uint2 pk;
      pk.x = (unsigned)f2b(v.x) | ((unsigned)f2b(v.y) << 16);
      pk.y = (unsigned)f2b(v.z) | ((unsigned)f2b(v.w) << 16);
      *(uint2*)(Xs + r * 1024 + (((c8 << 3)) ^ ((r & 7) << 4))) = pk;
    }
  }
  __syncthreads();

  // ---- layer 1: h1 = relu(X @ W1 + b1), computed as [h][b] ----
  {
    const char* Wg = (const char*)W1s + ((size_t)a << 19) + ((size_t)w << 16);
    f32x4 acc[4][4] = {};
    for (int ks = 0; ks < 16; ++ks) {
      int kb = (ks << 6) + (l4 << 4);  // byte offset of 16B k-chunk
      bf16x8 Bf[4];
#pragma unroll
      for (int bf = 0; bf < 4; ++bf) {
        int b = (bf << 4) + l15;
        Bf[bf] = *(const bf16x8*)(Xs + b * 1024 + (kb ^ ((b & 7) << 4)));
      }
#pragma unroll
      for (int hf = 0; hf < 4; ++hf) {
        bf16x8 Af = *(const bf16x8*)(Wg + (((hf << 4) + l15) << 10) + kb);
#pragma unroll
        for (int bf = 0; bf < 4; ++bf)
          acc[hf][bf] = __builtin_amdgcn_mfma_f32_16x16x32_bf16(Af, Bf[bf], acc[hf][bf], 0, 0, 0);
      }
    }
#pragma unroll
    for (int hf = 0; hf < 4; ++hf) {
      int hb = (w << 6) + (hf << 4) + (l4 << 2);
      float4 bias = *(const float4*)(b1 + (a << 9) + hb);
#pragma unroll
      for (int bf = 0; bf < 4; ++bf) {
        int b = (bf << 4) + l15;
        float x0 = fmaxf(acc[hf][bf][0] + bias.x, 0.f);
        float x1 = fmaxf(acc[hf][bf][1] + bias.y, 0.f);
        float x2 = fmaxf(acc[hf][bf][2] + bias.z, 0.f);
        float x3 = fmaxf(acc[hf][bf][3] + bias.w, 0.f);
        uint2 pk;
        pk.x = (unsigned)f2b(x0) | ((unsigned)f2b(x1) << 16);
        pk.y = (unsigned)f2b(x2) | ((unsigned)f2b(x3) << 16);
        *(uint2*)(H1s + b * 1024 + ((hb << 1) ^ ((b & 7) << 4))) = pk;
      }
    }
  }
  __syncthreads();

  // ---- layer 2 + fused layer 3: out = relu(h1 @ W2 + b2) . W3 + b3 ----
  {
    const char* Wg = (const char*)W2s + ((size_t)a << 19) + ((size_t)w << 16);
    f32x4 acc[4][4] = {};
    for (int ks = 0; ks < 16; ++ks) {
      int kb = (ks << 6) + (l4 << 4);
      bf16x8 Bf[4];
#pragma unroll
      for (int bf = 0; bf < 4; ++bf) {
        int b = (bf << 4) + l15;
        Bf[bf] = *(const bf16x8*)(H1s + b * 1024 + (kb ^ ((b & 7) << 4)));
      }
#pragma unroll
      for (int hf = 0; hf < 4; ++hf) {
        bf16x8 Af = *(const bf16x8*)(Wg + (((hf << 4) + l15) << 10) + kb);
#pragma unroll
        for (int bf = 0; bf < 4; ++bf)
          acc[hf][bf] = __builtin_amdgcn_mfma_f32_16x16x32_bf16(Af, Bf[bf], acc[hf][bf], 0, 0, 0);
      }
    }
    float part[4] = {0.f, 0.f, 0.f, 0.f};
#pragma unroll
    for (int hf = 0; hf < 4; ++hf) {
      int hb = (w << 6) + (hf << 4) + (l4 << 2);
      float4 bias = *(const float4*)(b2 + (a << 9) + hb);
      float4 w3v = *(const float4*)(W3 + (a << 9) + hb);
#pragma unroll
      for (int bf = 0; bf < 4; ++bf) {
        part[bf] += fmaxf(acc[hf][bf][0] + bias.x, 0.f) * w3v.x +
                    fmaxf(acc[hf][bf][1] + bias.y, 0.f) * w3v.y +
                    fmaxf(acc[hf][bf][2] + bias.z, 0.f) * w3v.z +
                    fmaxf(acc[hf][bf][3] + bias.w, 0.f) * w3v.w;
      }
    }
#pragma unroll
    for (int bf = 0; bf < 4; ++bf) {
      float p = part[bf];
      p += __shfl_xor(p, 16);
      p += __shfl_xor(p, 32);
      if (l4 == 0) outbuf[(w << 6) + (bf << 4) + l15] = p;
    }
  }
  __syncthreads();
  if (tid < 64 && tid < nrows) {
    float s = b3[a];
#pragma unroll
    for (int ww = 0; ww < 8; ++ww) s += outbuf[(ww << 6) + tid];
    out[perm[rowbase + tid]] = s;
  }
}

extern "C" void kernel_launch(void* const* d_in, const int* in_sizes, int n_in,
                              void* d_out, int out_size, void* d_ws, size_t ws_size,
                              hipStream_t stream) {
  const float* state = (const float*)d_in[0];
  const float* W1 = (const float*)d_in[1];
  const float* b1 = (const float*)d_in[2];
  const float* W2 = (const float*)d_in[3];
  const float* b2 = (const float*)d_in[4];
  const float* W3 = (const float*)d_in[5];
  const float* b3 = (const float*)d_in[6];
  const int* actions = (const int*)d_in[7];
  float* out = (float*)d_out;
  char* ws = (char*)d_ws;
  bf16* W1s = (bf16*)(ws + W1S_OFF);
  bf16* W2s = (bf16*)(ws + W2S_OFF);
  int* perm = (int*)(ws + PERM_OFF);
  int* meta = (int*)(ws + META_OFF);

  hipMemsetAsync(meta, 0, 66 * sizeof(int), stream);
  k_prep<<<2048, 256, 0, stream>>>(W1, W2, W1s, W2s);
  k_hist<<<NB / 256, 256, 0, stream>>>(actions, meta);
  k_scan<<<1, 1, 0, stream>>>(meta);
  k_scatter<<<NB / 256, 256, 0, stream>>>(actions, meta, perm);
  hipFuncSetAttribute((const void*)k_main, hipFuncAttributeMaxDynamicSharedMemorySize, 131072);
  k_main<<<272, 512, 131072, stream>>>(state, b1, b2, W3, b3, W1s, W2s, perm, meta, out);
}

// Round 3
// 94.595 us; speedup vs baseline: 2.1458x; 2.1458x over previous
//
#include <hip/hip_runtime.h>
#include <hip/hip_bf16.h>
#include <stdint.h>

typedef __hip_bfloat16 bf16;
typedef float f32x4 __attribute__((ext_vector_type(4)));
typedef short bf16x8 __attribute__((ext_vector_type(8)));

#define NB 16384
#define NA 16
#define ND 512
#define NH 512

// workspace layout (bytes)
#define W1S_OFF 0u
#define W2S_OFF 8388608u
#define PERM_OFF 16777216u
#define META_OFF 16842752u
// meta ints: [0..15]=cnt, [16..31]=off

__device__ __forceinline__ unsigned short f2b(float x) {
  unsigned int b = __float_as_uint(x);
  return (unsigned short)((b + 0x7FFFu + ((b >> 16) & 1u)) >> 16);  // RNE
}

// ---------------- prep: W[a][d][h] f32 -> Wt[a][h][d] bf16 (transpose + cast) -------------
__global__ __launch_bounds__(256) void k_prep(const float* __restrict__ W1,
                                              const float* __restrict__ W2,
                                              bf16* __restrict__ W1s,
                                              bf16* __restrict__ W2s) {
  __shared__ float tile[64][65];
  int blk = blockIdx.x;          // 0..2047
  int m = blk >> 6;              // matrix 0..31 (16 W1 + 16 W2)
  int tl = blk & 63;
  int td = tl >> 3, th = tl & 7; // 64x64 tile coords
  const float* src = (m < NA) ? (W1 + (size_t)m * (ND * NH)) : (W2 + (size_t)(m - NA) * (ND * NH));
  bf16* dst = (m < NA) ? (W1s + (size_t)m * (ND * NH)) : (W2s + (size_t)(m - NA) * (ND * NH));
  int t = threadIdx.x;
  int r = t >> 2, c0 = (t & 3) << 4;
  const float* sp = src + (size_t)(td * 64 + r) * NH + th * 64 + c0;
  float4 v0 = ((const float4*)sp)[0];
  float4 v1 = ((const float4*)sp)[1];
  float4 v2 = ((const float4*)sp)[2];
  float4 v3 = ((const float4*)sp)[3];
  float* tr = &tile[r][c0];
  tr[0] = v0.x; tr[1] = v0.y; tr[2] = v0.z; tr[3] = v0.w;
  tr[4] = v1.x; tr[5] = v1.y; tr[6] = v1.z; tr[7] = v1.w;
  tr[8] = v2.x; tr[9] = v2.y; tr[10] = v2.z; tr[11] = v2.w;
  tr[12] = v3.x; tr[13] = v3.y; tr[14] = v3.z; tr[15] = v3.w;
  __syncthreads();
  int hloc = t >> 2, dc = (t & 3) << 4;
  union { unsigned short us[16]; uint4 q[2]; } u;
#pragma unroll
  for (int i = 0; i < 16; ++i) u.us[i] = f2b(tile[dc + i][hloc]);
  uint4* dp = (uint4*)(dst + (size_t)(th * 64 + hloc) * ND + td * 64 + dc);
  dp[0] = u.q[0];
  dp[1] = u.q[1];
}

// ---------------- meta: histogram + scan + scatter, one block, all on-chip ----------------
__global__ __launch_bounds__(1024) void k_meta(const int* __restrict__ act,
                                               int* __restrict__ meta,
                                               int* __restrict__ perm) {
  __shared__ int bins[16][17];  // per-wave private bins (padded)
  __shared__ int cnt[16], off[16], cur[16];
  int tid = threadIdx.x;
  int w = tid >> 6;
  if (tid < 272) ((int*)bins)[tid] = 0;
  __syncthreads();
  int a[16];
#pragma unroll
  for (int i = 0; i < 16; ++i) {
    a[i] = act[tid + (i << 10)] & 15;
    atomicAdd(&bins[w][a[i]], 1);
  }
  __syncthreads();
  if (tid < 16) {
    int s = 0;
#pragma unroll
    for (int ww = 0; ww < 16; ++ww) s += bins[ww][tid];
    cnt[tid] = s;
  }
  __syncthreads();
  if (tid == 0) {
    int o = 0;
    for (int aa = 0; aa < 16; ++aa) {
      off[aa] = o;
      cur[aa] = o;
      o += cnt[aa];
    }
  }
  __syncthreads();
#pragma unroll
  for (int i = 0; i < 16; ++i) {
    int pos = atomicAdd(&cur[a[i]], 1);
    perm[pos] = tid + (i << 10);
  }
  if (tid < 16) {
    meta[tid] = cnt[tid];
    meta[16 + tid] = off[tid];
  }
}

// ---------------- fused grouped MLP ----------------
// XCD x (bid&7) owns actions 2x, 2x+1 -> 2MB weight working set per XCD L2.
// block: one 64-row tile. 512 threads = 8 waves; wave w owns h-rows [w*64, w*64+64).
// LDS: Xs 64KB (X tile, then overwritten with h1 via register round-trip), outbuf 2KB.
// A (weights, [h][k] bf16) streamed from L2 with depth-2 ping-pong prefetch.
__global__ __launch_bounds__(512, 4) void k_main(
    const float* __restrict__ state, const float* __restrict__ b1,
    const float* __restrict__ b2, const float* __restrict__ W3,
    const float* __restrict__ b3, const bf16* __restrict__ W1s,
    const bf16* __restrict__ W2s, const int* __restrict__ perm,
    const int* __restrict__ meta, float* __restrict__ out) {
  extern __shared__ char smem[];
  char* Xs = smem;
  float* outbuf = (float*)(smem + 65536);

  int bid = blockIdx.x;
  int xcd = bid & 7, slot = bid >> 3;
  int a0 = xcd << 1;
  int n0 = meta[a0], n1 = meta[a0 + 1];
  int nt0 = (n0 + 63) >> 6, nt1 = (n1 + 63) >> 6;
  int a, t;
  if (slot < nt0) {
    a = a0; t = slot;
  } else if (slot < nt0 + nt1) {
    a = a0 + 1; t = slot - nt0;
  } else {
    return;
  }
  int acnt = meta[a];
  int rowbase = meta[16 + a] + (t << 6);
  int nrows = acnt - (t << 6);
  nrows = nrows > 64 ? 64 : nrows;

  int tid = threadIdx.x;
  int lane = tid & 63;
  int w = tid >> 6;
  int l15 = lane & 15, l4 = lane >> 4;

  // ---- stage X tile -> LDS bf16, swizzle byte ^= (row&7)<<4 ----
  {
    int r = tid >> 3;
    int gr = (r < nrows) ? perm[rowbase + r] : -1;
    const float* srow = state + (size_t)(gr < 0 ? 0 : gr) * ND;
#pragma unroll
    for (int it = 0; it < 16; ++it) {
      int c8 = (tid & 7) + (it << 3);  // float4 chunk 0..127
      float4 v = make_float4(0.f, 0.f, 0.f, 0.f);
      if (gr >= 0) v = *(const float4*)(srow + (c8 << 2));
      uint2 pk;
      pk.x = (unsigned)f2b(v.x) | ((unsigned)f2b(v.y) << 16);
      pk.y = (unsigned)f2b(v.z) | ((unsigned)f2b(v.w) << 16);
      *(uint2*)(Xs + r * 1024 + (((c8 << 3)) ^ ((r & 7) << 4))) = pk;
    }
  }
  __syncthreads();

  uint2 h1p[16];

  // ---- layer 1: h1 = relu(X @ W1 + b1), [h][b], h1 kept in registers ----
  {
    const char* Wg = (const char*)W1s + ((size_t)a << 19) + ((size_t)w << 16) +
                     ((size_t)l15 << 10) + (l4 << 4);
    f32x4 acc[4][4] = {};
    bf16x8 A0[4], A1[4], Bf[4];
#pragma unroll
    for (int hf = 0; hf < 4; ++hf) A0[hf] = *(const bf16x8*)(Wg + hf * 16384);
    for (int ks = 0; ks < 16; ks += 2) {
      int kb = ks << 6;
#pragma unroll
      for (int bf = 0; bf < 4; ++bf) {
        int b = (bf << 4) + l15;
        Bf[bf] = *(const bf16x8*)(Xs + b * 1024 + ((kb + (l4 << 4)) ^ ((b & 7) << 4)));
      }
#pragma unroll
      for (int hf = 0; hf < 4; ++hf) A1[hf] = *(const bf16x8*)(Wg + hf * 16384 + kb + 64);
#pragma unroll
      for (int hf = 0; hf < 4; ++hf)
#pragma unroll
        for (int bf = 0; bf < 4; ++bf)
          acc[hf][bf] = __builtin_amdgcn_mfma_f32_16x16x32_bf16(A0[hf], Bf[bf], acc[hf][bf], 0, 0, 0);
#pragma unroll
      for (int bf = 0; bf < 4; ++bf) {
        int b = (bf << 4) + l15;
        Bf[bf] = *(const bf16x8*)(Xs + b * 1024 + ((kb + 64 + (l4 << 4)) ^ ((b & 7) << 4)));
      }
      if (ks + 2 < 16) {
#pragma unroll
        for (int hf = 0; hf < 4; ++hf) A0[hf] = *(const bf16x8*)(Wg + hf * 16384 + kb + 128);
      }
#pragma unroll
      for (int hf = 0; hf < 4; ++hf)
#pragma unroll
        for (int bf = 0; bf < 4; ++bf)
          acc[hf][bf] = __builtin_amdgcn_mfma_f32_16x16x32_bf16(A1[hf], Bf[bf], acc[hf][bf], 0, 0, 0);
    }
#pragma unroll
    for (int hf = 0; hf < 4; ++hf) {
      int hb = (w << 6) + (hf << 4) + (l4 << 2);
      float4 bias = *(const float4*)(b1 + (a << 9) + hb);
#pragma unroll
      for (int bf = 0; bf < 4; ++bf) {
        float x0 = fmaxf(acc[hf][bf][0] + bias.x, 0.f);
        float x1 = fmaxf(acc[hf][bf][1] + bias.y, 0.f);
        float x2 = fmaxf(acc[hf][bf][2] + bias.z, 0.f);
        float x3 = fmaxf(acc[hf][bf][3] + bias.w, 0.f);
        h1p[hf * 4 + bf].x = (unsigned)f2b(x0) | ((unsigned)f2b(x1) << 16);
        h1p[hf * 4 + bf].y = (unsigned)f2b(x2) | ((unsigned)f2b(x3) << 16);
      }
    }
  }
  __syncthreads();  // all waves done reading X
  // write h1 into Xs (X is dead)
#pragma unroll
  for (int hf = 0; hf < 4; ++hf) {
    int hb2 = ((w << 6) + (hf << 4) + (l4 << 2)) << 1;  // byte offset within row
#pragma unroll
    for (int bf = 0; bf < 4; ++bf) {
      int b = (bf << 4) + l15;
      *(uint2*)(Xs + b * 1024 + (hb2 ^ ((b & 7) << 4))) = h1p[hf * 4 + bf];
    }
  }
  __syncthreads();

  // ---- layer 2 + fused layer 3: out = relu(h1 @ W2 + b2) . W3 + b3 ----
  {
    const char* Wg = (const char*)W2s + ((size_t)a << 19) + ((size_t)w << 16) +
                     ((size_t)l15 << 10) + (l4 << 4);
    f32x4 acc[4][4] = {};
    bf16x8 A0[4], A1[4], Bf[4];
#pragma unroll
    for (int hf = 0; hf < 4; ++hf) A0[hf] = *(const bf16x8*)(Wg + hf * 16384);
    for (int ks = 0; ks < 16; ks += 2) {
      int kb = ks << 6;
#pragma unroll
      for (int bf = 0; bf < 4; ++bf) {
        int b = (bf << 4) + l15;
        Bf[bf] = *(const bf16x8*)(Xs + b * 1024 + ((kb + (l4 << 4)) ^ ((b & 7) << 4)));
      }
#pragma unroll
      for (int hf = 0; hf < 4; ++hf) A1[hf] = *(const bf16x8*)(Wg + hf * 16384 + kb + 64);
#pragma unroll
      for (int hf = 0; hf < 4; ++hf)
#pragma unroll
        for (int bf = 0; bf < 4; ++bf)
          acc[hf][bf] = __builtin_amdgcn_mfma_f32_16x16x32_bf16(A0[hf], Bf[bf], acc[hf][bf], 0, 0, 0);
#pragma unroll
      for (int bf = 0; bf < 4; ++bf) {
        int b = (bf << 4) + l15;
        Bf[bf] = *(const bf16x8*)(Xs + b * 1024 + ((kb + 64 + (l4 << 4)) ^ ((b & 7) << 4)));
      }
      if (ks + 2 < 16) {
#pragma unroll
        for (int hf = 0; hf < 4; ++hf) A0[hf] = *(const bf16x8*)(Wg + hf * 16384 + kb + 128);
      }
#pragma unroll
      for (int hf = 0; hf < 4; ++hf)
#pragma unroll
        for (int bf = 0; bf < 4; ++bf)
          acc[hf][bf] = __builtin_amdgcn_mfma_f32_16x16x32_bf16(A1[hf], Bf[bf], acc[hf][bf], 0, 0, 0);
    }
    float part[4] = {0.f, 0.f, 0.f, 0.f};
#pragma unroll
    for (int hf = 0; hf < 4; ++hf) {
      int hb = (w << 6) + (hf << 4) + (l4 << 2);
      float4 bias = *(const float4*)(b2 + (a << 9) + hb);
      float4 w3v = *(const float4*)(W3 + (a << 9) + hb);
#pragma unroll
      for (int bf = 0; bf < 4; ++bf) {
        part[bf] += fmaxf(acc[hf][bf][0] + bias.x, 0.f) * w3v.x +
                    fmaxf(acc[hf][bf][1] + bias.y, 0.f) * w3v.y +
                    fmaxf(acc[hf][bf][2] + bias.z, 0.f) * w3v.z +
                    fmaxf(acc[hf][bf][3] + bias.w, 0.f) * w3v.w;
      }
    }
#pragma unroll
    for (int bf = 0; bf < 4; ++bf) {
      float p = part[bf];
      p += __shfl_xor(p, 16);
      p += __shfl_xor(p, 32);
      if (l4 == 0) outbuf[(w << 6) + (bf << 4) + l15] = p;
    }
  }
  __syncthreads();
  if (tid < 64 && tid < nrows) {
    float s = b3[a];
#pragma unroll
    for (int ww = 0; ww < 8; ++ww) s += outbuf[(ww << 6) + tid];
    out[perm[rowbase + tid]] = s;
  }
}

extern "C" void kernel_launch(void* const* d_in, const int* in_sizes, int n_in,
                              void* d_out, int out_size, void* d_ws, size_t ws_size,
                              hipStream_t stream) {
  const float* state = (const float*)d_in[0];
  const float* W1 = (const float*)d_in[1];
  const float* b1 = (const float*)d_in[2];
  const float* W2 = (const float*)d_in[3];
  const float* b2 = (const float*)d_in[4];
  const float* W3 = (const float*)d_in[5];
  const float* b3 = (const float*)d_in[6];
  const int* actions = (const int*)d_in[7];
  float* out = (float*)d_out;
  char* ws = (char*)d_ws;
  bf16* W1s = (bf16*)(ws + W1S_OFF);
  bf16* W2s = (bf16*)(ws + W2S_OFF);
  int* perm = (int*)(ws + PERM_OFF);
  int* meta = (int*)(ws + META_OFF);

  k_meta<<<1, 1024, 0, stream>>>(actions, meta, perm);
  k_prep<<<2048, 256, 0, stream>>>(W1, W2, W1s, W2s);
  hipFuncSetAttribute((const void*)k_main, hipFuncAttributeMaxDynamicSharedMemorySize, 67584);
  k_main<<<512, 512, 67584, stream>>>(state, b1, b2, W3, b3, W1s, W2s, perm, meta, out);
}

// Round 4
// 87.649 us; speedup vs baseline: 2.3158x; 1.0792x over previous
//
#include <hip/hip_runtime.h>
#include <hip/hip_bf16.h>
#include <stdint.h>

typedef __hip_bfloat16 bf16;
typedef float f32x4 __attribute__((ext_vector_type(4)));
typedef short bf16x8 __attribute__((ext_vector_type(8)));

#define NB 16384
#define NA 16
#define ND 512
#define NH 512

// workspace layout (bytes)
#define W1S_OFF 0u
#define W2S_OFF 8388608u
#define PERM_OFF 16777216u
#define META_OFF 16842752u
// meta ints: [0..15]=cnt, [16..31]=off

__device__ __forceinline__ unsigned short f2b(float x) {
  unsigned int b = __float_as_uint(x);
  return (unsigned short)((b + 0x7FFFu + ((b >> 16) & 1u)) >> 16);  // RNE
}

// ---------------- prep: W[a][d][h] f32 -> fragment-tiled bf16 + (block 2048) meta ----------
// Tiled layout per action: blob[(h>>4)*16 + (k>>5)] of 1KB; within blob byte =
// ((k>>3)&3)*256 + (h&15)*16 + (k&7)*2.  A wave's MFMA A-fragment = 1KB contiguous.
__global__ __launch_bounds__(256) void k_prep(const float* __restrict__ W1,
                                              const float* __restrict__ W2,
                                              bf16* __restrict__ W1s,
                                              bf16* __restrict__ W2s,
                                              const int* __restrict__ act,
                                              int* __restrict__ meta,
                                              int* __restrict__ perm) {
  if (blockIdx.x == 2048) {
    // ---- meta: histogram + scan + scatter, one block, on-chip ----
    __shared__ int bins[4][16];
    __shared__ int cnt16[16], off16[16], cur16[16];
    int tid = threadIdx.x;
    int wv = tid >> 6;
    if (tid < 64) ((int*)bins)[tid] = 0;
    __syncthreads();
    for (int i = tid; i < NB; i += 256) atomicAdd(&bins[wv][act[i] & 15], 1);
    __syncthreads();
    if (tid < 16) cnt16[tid] = bins[0][tid] + bins[1][tid] + bins[2][tid] + bins[3][tid];
    __syncthreads();
    if (tid == 0) {
      int o = 0;
      for (int aa = 0; aa < 16; ++aa) {
        off16[aa] = o;
        cur16[aa] = o;
        o += cnt16[aa];
      }
    }
    __syncthreads();
    for (int i = tid; i < NB; i += 256) {
      int aa = act[i] & 15;
      perm[atomicAdd(&cur16[aa], 1)] = i;
    }
    if (tid < 16) {
      meta[tid] = cnt16[tid];
      meta[16 + tid] = off16[tid];
    }
    return;
  }
  __shared__ float tile[64][65];
  int blk = blockIdx.x;          // 0..2047
  int m = blk >> 6;              // matrix 0..31 (16 W1 + 16 W2)
  int tl = blk & 63;
  int td = tl >> 3, th = tl & 7; // 64x64 tile coords (td: k-dim, th: h-dim)
  const float* src = (m < NA) ? (W1 + (size_t)m * (ND * NH)) : (W2 + (size_t)(m - NA) * (ND * NH));
  char* dstb = (m < NA) ? ((char*)W1s + ((size_t)m << 19)) : ((char*)W2s + ((size_t)(m - NA) << 19));
  int t = threadIdx.x;
  int r = t >> 2, c0 = (t & 3) << 4;
  const float* sp = src + (size_t)(td * 64 + r) * NH + th * 64 + c0;
  float4 v0 = ((const float4*)sp)[0];
  float4 v1 = ((const float4*)sp)[1];
  float4 v2 = ((const float4*)sp)[2];
  float4 v3 = ((const float4*)sp)[3];
  float* tr = &tile[r][c0];
  tr[0] = v0.x; tr[1] = v0.y; tr[2] = v0.z; tr[3] = v0.w;
  tr[4] = v1.x; tr[5] = v1.y; tr[6] = v1.z; tr[7] = v1.w;
  tr[8] = v2.x; tr[9] = v2.y; tr[10] = v2.z; tr[11] = v2.w;
  tr[12] = v3.x; tr[13] = v3.y; tr[14] = v3.z; tr[15] = v3.w;
  __syncthreads();
  int hloc = t >> 2, dc = (t & 3) << 4;
  int h = th * 64 + hloc;        // output row (MFMA A row)
  int K0 = td * 64 + dc;         // k start (multiple of 16)
  union { unsigned short us[16]; uint4 q[2]; } u;
#pragma unroll
  for (int i = 0; i < 16; ++i) u.us[i] = f2b(tile[dc + i][hloc]);
  size_t ab = (size_t)((h >> 4) * 16 + (K0 >> 5)) * 1024 + (size_t)(h & 15) * 16;
  *(uint4*)(dstb + ab + (((K0 >> 3) & 3) << 8)) = u.q[0];
  *(uint4*)(dstb + ab + ((((K0 >> 3) + 1) & 3) << 8)) = u.q[1];
}

// ---------------- fused grouped MLP ----------------
// XCD x (bid&7) owns actions 2x, 2x+1 -> 2MB weight set per XCD L2.
// Block: 64-row tile, 512 threads = 8 waves; wave w owns h [w*64, w*64+64).
// LDS: Xs 64KB @0, H1s 64KB @64K, outbuf 2KB @128K. One barrier between layers.
// Weights: depth-4 register ping-pong (A[4][4]), fragment-tiled 1KB coalesced loads.
__global__ __launch_bounds__(512, 2) void k_main(
    const float* __restrict__ state, const float* __restrict__ b1,
    const float* __restrict__ b2, const float* __restrict__ W3,
    const float* __restrict__ b3, const bf16* __restrict__ W1s,
    const bf16* __restrict__ W2s, const int* __restrict__ perm,
    const int* __restrict__ meta, float* __restrict__ out) {
  extern __shared__ char smem[];
  char* Xs = smem;
  char* H1s = smem + 65536;
  float* outbuf = (float*)(smem + 131072);

  int bid = blockIdx.x;
  int xcd = bid & 7, slot = bid >> 3;
  int a0 = xcd << 1;
  int n0 = meta[a0], n1 = meta[a0 + 1];
  int nt0 = (n0 + 63) >> 6, nt1 = (n1 + 63) >> 6;
  int a, t;
  if (slot < nt0) {
    a = a0; t = slot;
  } else if (slot < nt0 + nt1) {
    a = a0 + 1; t = slot - nt0;
  } else {
    return;
  }
  int rowbase = meta[16 + a] + (t << 6);
  int nrows = meta[a] - (t << 6);
  nrows = nrows > 64 ? 64 : nrows;

  int tid = threadIdx.x;
  int lane = tid & 63;
  int w = tid >> 6;
  int l15 = lane & 15, l4 = lane >> 4;

  bf16x8 A[4][4];  // [slot][hf] depth-4 weight pipeline
  bf16x8 Bc[4], Bn[4];
  const char* Wl = (const char*)W1s + ((size_t)a << 19) + (w << 16) + (lane << 4);
  // issue layer-1 A preloads (slots 0..3) before staging; barrier drain absorbs latency
#pragma unroll
  for (int s = 0; s < 4; ++s)
#pragma unroll
    for (int hf = 0; hf < 4; ++hf)
      A[s][hf] = *(const bf16x8*)(Wl + hf * 16384 + s * 1024);

  // ---- stage X tile -> LDS bf16, swizzle byte ^= (row&7)<<4 ----
  {
    int r = tid >> 3;
    int gr = (r < nrows) ? perm[rowbase + r] : -1;
    const float* srow = state + (size_t)(gr < 0 ? 0 : gr) * ND;
#pragma unroll
    for (int it = 0; it < 16; ++it) {
      int c8 = (tid & 7) + (it << 3);  // float4 chunk 0..127
      float4 v = make_float4(0.f, 0.f, 0.f, 0.f);
      if (gr >= 0) v = *(const float4*)(srow + (c8 << 2));
      uint2 pk;
      pk.x = (unsigned)f2b(v.x) | ((unsigned)f2b(v.y) << 16);
      pk.y = (unsigned)f2b(v.z) | ((unsigned)f2b(v.w) << 16);
      *(uint2*)(Xs + r * 1024 + (((c8 << 3)) ^ ((r & 7) << 4))) = pk;
    }
  }
  __syncthreads();

  // ---- layer 1: h1 = relu(X @ W1 + b1), [h][b] ----
  {
    f32x4 acc[4][4] = {};
#pragma unroll
    for (int bf = 0; bf < 4; ++bf) {
      int b = (bf << 4) + l15;
      Bc[bf] = *(const bf16x8*)(Xs + b * 1024 + ((l4 << 4) ^ ((b & 7) << 4)));
    }
#pragma unroll
    for (int ks = 0; ks < 16; ++ks) {
      if (ks < 15) {
#pragma unroll
        for (int bf = 0; bf < 4; ++bf) {
          int b = (bf << 4) + l15;
          Bn[bf] = *(const bf16x8*)(Xs + b * 1024 + ((((ks + 1) << 6) + (l4 << 4)) ^ ((b & 7) << 4)));
        }
      }
#pragma unroll
      for (int hf = 0; hf < 4; ++hf)
#pragma unroll
        for (int bf = 0; bf < 4; ++bf)
          acc[hf][bf] = __builtin_amdgcn_mfma_f32_16x16x32_bf16(A[ks & 3][hf], Bc[bf], acc[hf][bf], 0, 0, 0);
      if (ks < 12) {
#pragma unroll
        for (int hf = 0; hf < 4; ++hf)
          A[ks & 3][hf] = *(const bf16x8*)(Wl + hf * 16384 + (ks + 4) * 1024);
      }
#pragma unroll
      for (int bf = 0; bf < 4; ++bf) Bc[bf] = Bn[bf];
    }
    // issue layer-2 A preloads now; they complete during the barrier drain
    const char* Wl2 = (const char*)W2s + ((size_t)a << 19) + (w << 16) + (lane << 4);
#pragma unroll
    for (int s = 0; s < 4; ++s)
#pragma unroll
      for (int hf = 0; hf < 4; ++hf)
        A[s][hf] = *(const bf16x8*)(Wl2 + hf * 16384 + s * 1024);
    // epilogue: bias + relu + pack bf16 -> H1s (swizzled)
#pragma unroll
    for (int hf = 0; hf < 4; ++hf) {
      int hb = (w << 6) + (hf << 4) + (l4 << 2);
      float4 bias = *(const float4*)(b1 + (a << 9) + hb);
#pragma unroll
      for (int bf = 0; bf < 4; ++bf) {
        int b = (bf << 4) + l15;
        float x0 = fmaxf(acc[hf][bf][0] + bias.x, 0.f);
        float x1 = fmaxf(acc[hf][bf][1] + bias.y, 0.f);
        float x2 = fmaxf(acc[hf][bf][2] + bias.z, 0.f);
        float x3 = fmaxf(acc[hf][bf][3] + bias.w, 0.f);
        uint2 pk;
        pk.x = (unsigned)f2b(x0) | ((unsigned)f2b(x1) << 16);
        pk.y = (unsigned)f2b(x2) | ((unsigned)f2b(x3) << 16);
        *(uint2*)(H1s + b * 1024 + (((hb << 1)) ^ ((b & 7) << 4))) = pk;
      }
    }
  }
  __syncthreads();

  // ---- layer 2 + fused layer 3: out = relu(h1 @ W2 + b2) . W3 + b3 ----
  {
    f32x4 acc[4][4] = {};
    const char* Wl2 = (const char*)W2s + ((size_t)a << 19) + (w << 16) + (lane << 4);
#pragma unroll
    for (int bf = 0; bf < 4; ++bf) {
      int b = (bf << 4) + l15;
      Bc[bf] = *(const bf16x8*)(H1s + b * 1024 + ((l4 << 4) ^ ((b & 7) << 4)));
    }
#pragma unroll
    for (int ks = 0; ks < 16; ++ks) {
      if (ks < 15) {
#pragma unroll
        for (int bf = 0; bf < 4; ++bf) {
          int b = (bf << 4) + l15;
          Bn[bf] = *(const bf16x8*)(H1s + b * 1024 + ((((ks + 1) << 6) + (l4 << 4)) ^ ((b & 7) << 4)));
        }
      }
#pragma unroll
      for (int hf = 0; hf < 4; ++hf)
#pragma unroll
        for (int bf = 0; bf < 4; ++bf)
          acc[hf][bf] = __builtin_amdgcn_mfma_f32_16x16x32_bf16(A[ks & 3][hf], Bc[bf], acc[hf][bf], 0, 0, 0);
      if (ks < 12) {
#pragma unroll
        for (int hf = 0; hf < 4; ++hf)
          A[ks & 3][hf] = *(const bf16x8*)(Wl2 + hf * 16384 + (ks + 4) * 1024);
      }
#pragma unroll
      for (int bf = 0; bf < 4; ++bf) Bc[bf] = Bn[bf];
    }
    float part[4] = {0.f, 0.f, 0.f, 0.f};
#pragma unroll
    for (int hf = 0; hf < 4; ++hf) {
      int hb = (w << 6) + (hf << 4) + (l4 << 2);
      float4 bias = *(const float4*)(b2 + (a << 9) + hb);
      float4 w3v = *(const float4*)(W3 + (a << 9) + hb);
#pragma unroll
      for (int bf = 0; bf < 4; ++bf) {
        part[bf] += fmaxf(acc[hf][bf][0] + bias.x, 0.f) * w3v.x +
                    fmaxf(acc[hf][bf][1] + bias.y, 0.f) * w3v.y +
                    fmaxf(acc[hf][bf][2] + bias.z, 0.f) * w3v.z +
                    fmaxf(acc[hf][bf][3] + bias.w, 0.f) * w3v.w;
      }
    }
#pragma unroll
    for (int bf = 0; bf < 4; ++bf) {
      float p = part[bf];
      p += __shfl_xor(p, 16);
      p += __shfl_xor(p, 32);
      if (l4 == 0) outbuf[(w << 6) + (bf << 4) + l15] = p;
    }
  }
  __syncthreads();
  if (tid < 64 && tid < nrows) {
    float s = b3[a];
#pragma unroll
    for (int ww = 0; ww < 8; ++ww) s += outbuf[(ww << 6) + tid];
    out[perm[rowbase + tid]] = s;
  }
}

extern "C" void kernel_launch(void* const* d_in, const int* in_sizes, int n_in,
                              void* d_out, int out_size, void* d_ws, size_t ws_size,
                              hipStream_t stream) {
  const float* state = (const float*)d_in[0];
  const float* W1 = (const float*)d_in[1];
  const float* b1 = (const float*)d_in[2];
  const float* W2 = (const float*)d_in[3];
  const float* b2 = (const float*)d_in[4];
  const float* W3 = (const float*)d_in[5];
  const float* b3 = (const float*)d_in[6];
  const int* actions = (const int*)d_in[7];
  float* out = (float*)d_out;
  char* ws = (char*)d_ws;
  bf16* W1s = (bf16*)(ws + W1S_OFF);
  bf16* W2s = (bf16*)(ws + W2S_OFF);
  int* perm = (int*)(ws + PERM_OFF);
  int* meta = (int*)(ws + META_OFF);

  k_prep<<<2049, 256, 0, stream>>>(W1, W2, W1s, W2s, actions, meta, perm);
  hipFuncSetAttribute((const void*)k_main, hipFuncAttributeMaxDynamicSharedMemorySize, 133120);
  k_main<<<512, 512, 133120, stream>>>(state, b1, b2, W3, b3, W1s, W2s, perm, meta, out);
}

// Round 5
// 75.188 us; speedup vs baseline: 2.6996x; 1.1657x over previous
//
#include <hip/hip_runtime.h>
#include <hip/hip_bf16.h>
#include <stdint.h>

typedef __hip_bfloat16 bf16;
typedef float f32x4 __attribute__((ext_vector_type(4)));
typedef short bf16x8 __attribute__((ext_vector_type(8)));

#define NB 16384
#define NA 16
#define ND 512
#define NH 512
#define TR 80  // rows per tile: ceil(1024/80)*2 ~ 26 tiles/XCD-pair <= 32 slots -> no tail

// workspace layout (bytes)
#define W1S_OFF 0u
#define W2S_OFF 8388608u
#define PERM_OFF 16777216u
#define META_OFF 16842752u
// meta ints: [0..15]=cnt, [16..31]=off

__device__ __forceinline__ unsigned short f2b(float x) {
  unsigned int b = __float_as_uint(x);
  return (unsigned short)((b + 0x7FFFu + ((b >> 16) & 1u)) >> 16);  // RNE
}

// ---------------- prep: W[a][d][h] f32 -> fragment-tiled bf16 + (block 2048) meta ----------
// Tiled layout per action: blob[(h>>4)*16 + (k>>5)] of 1KB; within blob byte =
// ((k>>3)&3)*256 + (h&15)*16 + (k&7)*2.  A wave's MFMA A-fragment = 1KB contiguous.
__global__ __launch_bounds__(256) void k_prep(const float* __restrict__ W1,
                                              const float* __restrict__ W2,
                                              bf16* __restrict__ W1s,
                                              bf16* __restrict__ W2s,
                                              const int* __restrict__ act,
                                              int* __restrict__ meta,
                                              int* __restrict__ perm) {
  if (blockIdx.x == 2048) {
    __shared__ int bins[4][16];
    __shared__ int cnt16[16], off16[16], cur16[16];
    int tid = threadIdx.x;
    int wv = tid >> 6;
    if (tid < 64) ((int*)bins)[tid] = 0;
    __syncthreads();
    for (int i = tid; i < NB; i += 256) atomicAdd(&bins[wv][act[i] & 15], 1);
    __syncthreads();
    if (tid < 16) cnt16[tid] = bins[0][tid] + bins[1][tid] + bins[2][tid] + bins[3][tid];
    __syncthreads();
    if (tid == 0) {
      int o = 0;
      for (int aa = 0; aa < 16; ++aa) {
        off16[aa] = o;
        cur16[aa] = o;
        o += cnt16[aa];
      }
    }
    __syncthreads();
    for (int i = tid; i < NB; i += 256) {
      int aa = act[i] & 15;
      perm[atomicAdd(&cur16[aa], 1)] = i;
    }
    if (tid < 16) {
      meta[tid] = cnt16[tid];
      meta[16 + tid] = off16[tid];
    }
    return;
  }
  __shared__ float tile[64][65];
  int blk = blockIdx.x;          // 0..2047
  int m = blk >> 6;              // matrix 0..31 (16 W1 + 16 W2)
  int tl = blk & 63;
  int td = tl >> 3, th = tl & 7; // 64x64 tile coords (td: k-dim, th: h-dim)
  const float* src = (m < NA) ? (W1 + (size_t)m * (ND * NH)) : (W2 + (size_t)(m - NA) * (ND * NH));
  char* dstb = (m < NA) ? ((char*)W1s + ((size_t)m << 19)) : ((char*)W2s + ((size_t)(m - NA) << 19));
  int t = threadIdx.x;
  int r = t >> 2, c0 = (t & 3) << 4;
  const float* sp = src + (size_t)(td * 64 + r) * NH + th * 64 + c0;
  float4 v0 = ((const float4*)sp)[0];
  float4 v1 = ((const float4*)sp)[1];
  float4 v2 = ((const float4*)sp)[2];
  float4 v3 = ((const float4*)sp)[3];
  float* tr = &tile[r][c0];
  tr[0] = v0.x; tr[1] = v0.y; tr[2] = v0.z; tr[3] = v0.w;
  tr[4] = v1.x; tr[5] = v1.y; tr[6] = v1.z; tr[7] = v1.w;
  tr[8] = v2.x; tr[9] = v2.y; tr[10] = v2.z; tr[11] = v2.w;
  tr[12] = v3.x; tr[13] = v3.y; tr[14] = v3.z; tr[15] = v3.w;
  __syncthreads();
  int hloc = t >> 2, dc = (t & 3) << 4;
  int h = th * 64 + hloc;        // output row (MFMA A row)
  int K0 = td * 64 + dc;         // k start (multiple of 16)
  union { unsigned short us[16]; uint4 q[2]; } u;
#pragma unroll
  for (int i = 0; i < 16; ++i) u.us[i] = f2b(tile[dc + i][hloc]);
  size_t ab = (size_t)((h >> 4) * 16 + (K0 >> 5)) * 1024 + (size_t)(h & 15) * 16;
  *(uint4*)(dstb + ab + (((K0 >> 3) & 3) << 8)) = u.q[0];
  *(uint4*)(dstb + ab + ((((K0 >> 3) + 1) & 3) << 8)) = u.q[1];
}

// ---------------- fused grouped MLP ----------------
// XCD x (bid&7) owns actions 2x,2x+1 -> 2MB weight set per XCD L2. Grid 256 = 32 slots/XCD,
// tiles/pair ~26 <= 32 -> every tile resident concurrently (no serial tail).
// Block: 80-row tile, 512 threads = 8 waves; wave w owns h [w*64, w*64+64) x 80 batch cols.
// LDS: Xs 80KB @0 (X, then h1 via register round-trip), outbuf 2.5KB @81920.
// Weights: depth-4 register ping-pong (A[4][4]), fragment-tiled 1KB coalesced loads.
__global__ __launch_bounds__(512, 2) void k_main(
    const float* __restrict__ state, const float* __restrict__ b1,
    const float* __restrict__ b2, const float* __restrict__ W3,
    const float* __restrict__ b3, const bf16* __restrict__ W1s,
    const bf16* __restrict__ W2s, const int* __restrict__ perm,
    const int* __restrict__ meta, float* __restrict__ out) {
  extern __shared__ char smem[];
  char* Xs = smem;
  float* outbuf = (float*)(smem + 81920);

  int bid = blockIdx.x;
  int xcd = bid & 7, slot = bid >> 3;
  int a0 = xcd << 1;
  int n0 = meta[a0], n1 = meta[a0 + 1];
  int nt0 = (n0 + TR - 1) / TR, nt1 = (n1 + TR - 1) / TR;
  int a, t;
  if (slot < nt0) {
    a = a0; t = slot;
  } else if (slot < nt0 + nt1) {
    a = a0 + 1; t = slot - nt0;
  } else {
    return;
  }
  int rowbase = meta[16 + a] + t * TR;
  int nrows = meta[a] - t * TR;
  nrows = nrows > TR ? TR : nrows;

  int tid = threadIdx.x;
  int lane = tid & 63;
  int w = tid >> 6;
  int l15 = lane & 15, l4 = lane >> 4;

  bf16x8 A[4][4];  // [slot][hf] depth-4 weight pipeline
  bf16x8 Bc[5], Bn[5];
  const char* Wl = (const char*)W1s + ((size_t)a << 19) + (w << 16) + (lane << 4);
#pragma unroll
  for (int s = 0; s < 4; ++s)
#pragma unroll
    for (int hf = 0; hf < 4; ++hf)
      A[s][hf] = *(const bf16x8*)(Wl + hf * 16384 + s * 1024);

  // ---- stage X tile -> LDS bf16, swizzle byte ^= (row&7)<<4 ----
  {
#pragma unroll
    for (int it = 0; it < 20; ++it) {
      int c = tid + (it << 9);       // 0..10239
      int row = c >> 7, chunk = c & 127;
      int gr = (row < nrows) ? perm[rowbase + row] : -1;
      float4 v = make_float4(0.f, 0.f, 0.f, 0.f);
      if (gr >= 0) v = *(const float4*)(state + (size_t)gr * ND + (chunk << 2));
      uint2 pk;
      pk.x = (unsigned)f2b(v.x) | ((unsigned)f2b(v.y) << 16);
      pk.y = (unsigned)f2b(v.z) | ((unsigned)f2b(v.w) << 16);
      *(uint2*)(Xs + row * 1024 + ((chunk << 3) ^ ((row & 7) << 4))) = pk;
    }
  }
  __syncthreads();

  uint2 h1p[20];

  // ---- layer 1: h1 = relu(X @ W1 + b1), [h][b], h1 kept in registers ----
  {
    f32x4 acc[4][5] = {};
#pragma unroll
    for (int bf = 0; bf < 5; ++bf) {
      int b = (bf << 4) + l15;
      Bc[bf] = *(const bf16x8*)(Xs + b * 1024 + ((l4 << 4) ^ ((b & 7) << 4)));
    }
#pragma unroll
    for (int ks = 0; ks < 16; ++ks) {
      if (ks < 15) {
#pragma unroll
        for (int bf = 0; bf < 5; ++bf) {
          int b = (bf << 4) + l15;
          Bn[bf] = *(const bf16x8*)(Xs + b * 1024 + ((((ks + 1) << 6) + (l4 << 4)) ^ ((b & 7) << 4)));
        }
      }
#pragma unroll
      for (int hf = 0; hf < 4; ++hf)
#pragma unroll
        for (int bf = 0; bf < 5; ++bf)
          acc[hf][bf] = __builtin_amdgcn_mfma_f32_16x16x32_bf16(A[ks & 3][hf], Bc[bf], acc[hf][bf], 0, 0, 0);
      if (ks < 12) {
#pragma unroll
        for (int hf = 0; hf < 4; ++hf)
          A[ks & 3][hf] = *(const bf16x8*)(Wl + hf * 16384 + (ks + 4) * 1024);
      }
#pragma unroll
      for (int bf = 0; bf < 5; ++bf) Bc[bf] = Bn[bf];
    }
    // issue layer-2 A preloads now; latency hides under epilogue + barrier
    const char* Wl2 = (const char*)W2s + ((size_t)a << 19) + (w << 16) + (lane << 4);
#pragma unroll
    for (int s = 0; s < 4; ++s)
#pragma unroll
      for (int hf = 0; hf < 4; ++hf)
        A[s][hf] = *(const bf16x8*)(Wl2 + hf * 16384 + s * 1024);
    // epilogue: bias + relu + pack bf16 into registers
#pragma unroll
    for (int hf = 0; hf < 4; ++hf) {
      int hb = (w << 6) + (hf << 4) + (l4 << 2);
      float4 bias = *(const float4*)(b1 + (a << 9) + hb);
#pragma unroll
      for (int bf = 0; bf < 5; ++bf) {
        float x0 = fmaxf(acc[hf][bf][0] + bias.x, 0.f);
        float x1 = fmaxf(acc[hf][bf][1] + bias.y, 0.f);
        float x2 = fmaxf(acc[hf][bf][2] + bias.z, 0.f);
        float x3 = fmaxf(acc[hf][bf][3] + bias.w, 0.f);
        h1p[hf * 5 + bf].x = (unsigned)f2b(x0) | ((unsigned)f2b(x1) << 16);
        h1p[hf * 5 + bf].y = (unsigned)f2b(x2) | ((unsigned)f2b(x3) << 16);
      }
    }
  }
  __syncthreads();  // all waves done reading X
  // write h1 into Xs (X is dead)
#pragma unroll
  for (int hf = 0; hf < 4; ++hf) {
    int hb2 = ((w << 6) + (hf << 4) + (l4 << 2)) << 1;  // byte offset within row
#pragma unroll
    for (int bf = 0; bf < 5; ++bf) {
      int b = (bf << 4) + l15;
      *(uint2*)(Xs + b * 1024 + (hb2 ^ ((b & 7) << 4))) = h1p[hf * 5 + bf];
    }
  }
  __syncthreads();

  // ---- layer 2 + fused layer 3: out = relu(h1 @ W2 + b2) . W3 + b3 ----
  {
    f32x4 acc[4][5] = {};
    const char* Wl2 = (const char*)W2s + ((size_t)a << 19) + (w << 16) + (lane << 4);
#pragma unroll
    for (int bf = 0; bf < 5; ++bf) {
      int b = (bf << 4) + l15;
      Bc[bf] = *(const bf16x8*)(Xs + b * 1024 + ((l4 << 4) ^ ((b & 7) << 4)));
    }
#pragma unroll
    for (int ks = 0; ks < 16; ++ks) {
      if (ks < 15) {
#pragma unroll
        for (int bf = 0; bf < 5; ++bf) {
          int b = (bf << 4) + l15;
          Bn[bf] = *(const bf16x8*)(Xs + b * 1024 + ((((ks + 1) << 6) + (l4 << 4)) ^ ((b & 7) << 4)));
        }
      }
#pragma unroll
      for (int hf = 0; hf < 4; ++hf)
#pragma unroll
        for (int bf = 0; bf < 5; ++bf)
          acc[hf][bf] = __builtin_amdgcn_mfma_f32_16x16x32_bf16(A[ks & 3][hf], Bc[bf], acc[hf][bf], 0, 0, 0);
      if (ks < 12) {
#pragma unroll
        for (int hf = 0; hf < 4; ++hf)
          A[ks & 3][hf] = *(const bf16x8*)(Wl2 + hf * 16384 + (ks + 4) * 1024);
      }
#pragma unroll
      for (int bf = 0; bf < 5; ++bf) Bc[bf] = Bn[bf];
    }
    float part[5] = {0.f, 0.f, 0.f, 0.f, 0.f};
#pragma unroll
    for (int hf = 0; hf < 4; ++hf) {
      int hb = (w << 6) + (hf << 4) + (l4 << 2);
      float4 bias = *(const float4*)(b2 + (a << 9) + hb);
      float4 w3v = *(const float4*)(W3 + (a << 9) + hb);
#pragma unroll
      for (int bf = 0; bf < 5; ++bf) {
        part[bf] += fmaxf(acc[hf][bf][0] + bias.x, 0.f) * w3v.x +
                    fmaxf(acc[hf][bf][1] + bias.y, 0.f) * w3v.y +
                    fmaxf(acc[hf][bf][2] + bias.z, 0.f) * w3v.z +
                    fmaxf(acc[hf][bf][3] + bias.w, 0.f) * w3v.w;
      }
    }
#pragma unroll
    for (int bf = 0; bf < 5; ++bf) {
      float p = part[bf];
      p += __shfl_xor(p, 16);
      p += __shfl_xor(p, 32);
      if (l4 == 0) outbuf[w * TR + (bf << 4) + l15] = p;
    }
  }
  __syncthreads();
  if (tid < nrows) {
    float s = b3[a];
#pragma unroll
    for (int ww = 0; ww < 8; ++ww) s += outbuf[ww * TR + tid];
    out[perm[rowbase + tid]] = s;
  }
}

extern "C" void kernel_launch(void* const* d_in, const int* in_sizes, int n_in,
                              void* d_out, int out_size, void* d_ws, size_t ws_size,
                              hipStream_t stream) {
  const float* state = (const float*)d_in[0];
  const float* W1 = (const float*)d_in[1];
  const float* b1 = (const float*)d_in[2];
  const float* W2 = (const float*)d_in[3];
  const float* b2 = (const float*)d_in[4];
  const float* W3 = (const float*)d_in[5];
  const float* b3 = (const float*)d_in[6];
  const int* actions = (const int*)d_in[7];
  float* out = (float*)d_out;
  char* ws = (char*)d_ws;
  bf16* W1s = (bf16*)(ws + W1S_OFF);
  bf16* W2s = (bf16*)(ws + W2S_OFF);
  int* perm = (int*)(ws + PERM_OFF);
  int* meta = (int*)(ws + META_OFF);

  k_prep<<<2049, 256, 0, stream>>>(W1, W2, W1s, W2s, actions, meta, perm);
  hipFuncSetAttribute((const void*)k_main, hipFuncAttributeMaxDynamicSharedMemorySize, 84480);
  k_main<<<256, 512, 84480, stream>>>(state, b1, b2, W3, b3, W1s, W2s, perm, meta, out);
}